// Round 6
// baseline (78.411 us; speedup 1.0000x reference)
//
#include <hip/hip_runtime.h>
#include <hip/hip_bf16.h>
#include <math.h>

#ifndef M_PI
#define M_PI 3.14159265358979323846
#endif

constexpr int N    = 1024;
constexpr int M    = 4096;
constexpr int RANK = 32;
constexpr float PHI1 = -1.5339807878856412e-3f;   // -2*pi/4096

typedef __attribute__((ext_vector_type(8))) short bf16x8;
typedef __attribute__((ext_vector_type(4))) float f32x4;

// Branch-free fast softplus: max(x,0) + log(1+e^-|x|); HW exp/log, err ~1e-7.
__device__ __forceinline__ float softplus_f(float x) {
    const float t = __expf(-fabsf(x));
    return fmaxf(x, 0.0f) + __logf(1.0f + t);
}

// HW RNE bf16 converts.
__device__ __forceinline__ unsigned pack_bf16x2(float a, float b) {
    __hip_bfloat162 p;
    p.x = __float2bfloat16(a);
    p.y = __float2bfloat16(b);
    unsigned r;
    __builtin_memcpy(&r, &p, 4);
    return r;
}
__device__ __forceinline__ unsigned short bf16_1(float x) {
    __hip_bfloat16 b = __float2bfloat16(x);
    unsigned short r;
    __builtin_memcpy(&r, &b, 2);
    return r;
}

// ---------------------------------------------------------------------------
// A-side Taylor terms for one (n,d): o = {R0, -I0, R1, -I1, R2, -I2}.
// ---------------------------------------------------------------------------
__device__ __forceinline__ void a_terms(float w, float t, float mcF, float* o) {
    const float sw = softplus_f(w);
    const float a1 = PHI1 * t;
    float s0, c0; __sincosf(a1 * mcF, &s0, &c0);
    const float R0 = sw * c0,  I0 = sw * s0;
    const float R1 = -a1 * I0, I1 = a1 * R0;
    const float h  = 0.5f * a1;
    const float R2 = -h * I1,  I2 = h * R1;
    o[0] = R0; o[1] = -I0; o[2] = R1; o[3] = -I1; o[4] = R2; o[5] = -I2;
}

// ===========================================================================
// R22 dft_plane: fused DFT via mod-16 split + bf16 B-plane emission.
// Block (c,d), c=0..15, d=0..31 (grid 16x32 = 512 = 2/CU, 8 waves/CU —
// double R21's latency hiding).  For m ≡ c (mod 16), the needed stage-1
// rows are exactly r = c + 16*rr (rr=0..3): 4 rows/block, 512 blocks =
// same 2048 row-DFTs as mod-8 — ZERO stage-1 redundancy.  Per-thread
// serial work halves vs R21 (1 r-row, 1 m).
// Instead of Hf, writes the einsum's 6 bf16 B-planes directly:
// P chunk per 64-m tile = [p][mloc][40] u16 (30720 B) — the exact LDS
// image einsum stages, so einsum staging becomes a pure copy and the
// per-(m,d) conversion happens ONCE chip-wide (was x16 across nG blocks).
// Same recurrences as validated R21 -> bit-identical values.
// LDS 18.1 KB.
// ===========================================================================
__global__ __launch_bounds__(256) void dft_plane(const float* __restrict__ H,
                                                 unsigned short* __restrict__ P) {
    __shared__ float  sh[M];          // 16 KB softplus'd row
    __shared__ float2 sG[4 * 65];     // 2.08 KB  [rr][k0], stride 65
    const int c   = blockIdx.x;       // 0..15
    const int d   = blockIdx.y;       // 0..31
    const int tid = threadIdx.x;

    const float4* H4 = (const float4*)(H + d * M);
    for (int i = tid; i < M / 4; i += 256) {
        const float4 v = H4[i];
        ((float4*)sh)[i] = make_float4(softplus_f(v.x), softplus_f(v.y),
                                       softplus_f(v.z), softplus_f(v.w));
    }
    __syncthreads();

    // ---- stage 1: G[r][k0] = sum_k1 sh[64*k1+k0] e^{-2pi i k1 r/64},
    //      r = c + 16*rr, rr = tid>>6 (one row per thread).
    {
        const int k0 = tid & 63;
        const int rr = tid >> 6;            // 0..3
        const int r  = c + 16 * rr;
        float s0, c0;
        __sincosf((-2.0f * (float)M_PI / 64.0f) * (float)r, &s0, &c0);
        float twR = 1.f, twI = 0.f, aR = 0.f, aI = 0.f;
        for (int k1 = 0; k1 < 64; ++k1) {
            const float h = sh[(k1 << 6) + k0];
            aR = fmaf(h, twR, aR);  aI = fmaf(h, twI, aI);
            const float nR = fmaf(twR, c0, -twI * s0);
            const float nI = fmaf(twR, s0,  twI * c0);
            twR = nR; twI = nI;
        }
        sG[rr * 65 + k0] = make_float2(aR, aI);
    }
    __syncthreads();

    // ---- stage 2 + plane emission: m = c + 16*tid (one m per thread).
    //      m&63 = c + 16*(tid&3) -> row rr = tid&3.
    const int m  = c + 16 * tid;
    const int rr = tid & 3;
    float ss, sc; __sincosf(PHI1 * (float)m, &ss, &sc);
    float tR_ = 1.f, tI_ = 0.f, accR = 0.f, accI = 0.f;
    #pragma unroll 8
    for (int k0 = 0; k0 < 64; ++k0) {
        const float2 g = sG[rr * 65 + k0];
        accR = fmaf(tR_, g.x, fmaf(-tI_, g.y, accR));
        accI = fmaf(tR_, g.y, fmaf( tI_, g.x, accI));
        const float nR = fmaf(tR_, sc, -tI_ * ss);
        const float nI = fmaf(tR_, ss,  tI_ * sc);
        tR_ = nR; tI_ = nI;
    }

    const int mG = m >> 6, mloc = m & 63;
    const float dlt = (float)mloc - 32.0f;
    const float dq  = dlt * dlt;
    // chunk layout (u16): [p][mloc][40], p-stride 2560, chunk-stride 15360.
    unsigned short* cp = P + (size_t)mG * 15360 + (size_t)mloc * 40 + d;
    cp[0]        = bf16_1(accR);
    cp[2560]     = bf16_1(accI);
    cp[2 * 2560] = bf16_1(accR * dlt);
    cp[3 * 2560] = bf16_1(accI * dlt);
    cp[4 * 2560] = bf16_1(accR * dq);
    cp[5 * 2560] = bf16_1(accI * dq);
}

// ===========================================================================
// R21 fused DFT writing Hf (kept for the cplx ws path; validated 78.3 us).
// ===========================================================================
__global__ __launch_bounds__(256) void dft_bal(const float* __restrict__ H,
                                               float* __restrict__ HfR,
                                               float* __restrict__ HfI) {
    __shared__ float  sh[M];
    __shared__ float2 sG[8 * 65];
    const int c   = blockIdx.x;       // 0..7
    const int d   = blockIdx.y;       // 0..31
    const int tid = threadIdx.x;

    const float4* H4 = (const float4*)(H + d * M);
    for (int i = tid; i < M / 4; i += 256) {
        const float4 v = H4[i];
        ((float4*)sh)[i] = make_float4(softplus_f(v.x), softplus_f(v.y),
                                       softplus_f(v.z), softplus_f(v.w));
    }
    __syncthreads();

    {
        const int k0   = tid & 63;
        const int rgrp = tid >> 6;
        const int rr0  = rgrp * 2;
        const int r0   = c + 8 * rr0;
        const int r1   = r0 + 8;
        float s0, c0, s1, c1;
        __sincosf((-2.0f * (float)M_PI / 64.0f) * (float)r0, &s0, &c0);
        __sincosf((-2.0f * (float)M_PI / 64.0f) * (float)r1, &s1, &c1);
        float twR0 = 1.f, twI0 = 0.f, aR0 = 0.f, aI0 = 0.f;
        float twR1 = 1.f, twI1 = 0.f, aR1 = 0.f, aI1 = 0.f;
        for (int k1 = 0; k1 < 64; ++k1) {
            const float h = sh[(k1 << 6) + k0];
            aR0 = fmaf(h, twR0, aR0);  aI0 = fmaf(h, twI0, aI0);
            aR1 = fmaf(h, twR1, aR1);  aI1 = fmaf(h, twI1, aI1);
            float nR = fmaf(twR0, c0, -twI0 * s0);
            float nI = fmaf(twR0, s0,  twI0 * c0);
            twR0 = nR; twI0 = nI;
            nR = fmaf(twR1, c1, -twI1 * s1);
            nI = fmaf(twR1, s1,  twI1 * c1);
            twR1 = nR; twI1 = nI;
        }
        sG[rr0 * 65 + k0]       = make_float2(aR0, aI0);
        sG[(rr0 + 1) * 65 + k0] = make_float2(aR1, aI1);
    }
    __syncthreads();

    const int rr = tid & 7;
    #pragma unroll
    for (int j = 0; j < 2; ++j) {
        const int m = c + 8 * (tid + 256 * j);
        float ss, sc; __sincosf(PHI1 * (float)m, &ss, &sc);
        float tR_ = 1.f, tI_ = 0.f, accR = 0.f, accI = 0.f;
        #pragma unroll 8
        for (int k0 = 0; k0 < 64; ++k0) {
            const float2 g = sG[rr * 65 + k0];
            accR = fmaf(tR_, g.x, fmaf(-tI_, g.y, accR));
            accI = fmaf(tR_, g.y, fmaf( tI_, g.x, accI));
            const float nR = fmaf(tR_, sc, -tI_ * ss);
            const float nI = fmaf(tR_, ss,  tI_ * sc);
            tR_ = nR; tI_ = nI;
        }
        HfR[d * M + m] = accR;
        HfI[d * M + m] = accI;
    }
}

// ===========================================================================
// MFMA einsum — R22: staging is now a pure coalesced uint4 copy of the
// precomputed plane chunk (30720 B) into LDS.  Zero staging VALU; all
// per-(m,d) conversion moved to dft_plane (x1 chip-wide instead of x16).
// Pad cols 32..39 hold garbage but MFMA reads only cols 0..31.
// grid (64 mG, 16 nG), block 256, LDS 30.7 KB -> 4 blocks/CU.
// ===========================================================================
__global__ __launch_bounds__(256, 4) void einsum_mfma(const float* __restrict__ W,
                                                      const float* __restrict__ tau,
                                                      const unsigned short* __restrict__ P,
                                                      float* __restrict__ out_f) {
    __shared__ __attribute__((aligned(16))) unsigned short sB[6][64][40]; // 30720 B
    const int tid   = threadIdx.x;
    const int mBase = blockIdx.x * 64;
    const int nBase = blockIdx.y * 64;

    const int wv = tid >> 6, lane = tid & 63;
    const int q = lane >> 4, l = lane & 15;
    const int nA = nBase + wv * 16 + l;
    const int d8 = q << 3;
    const float mcF = (float)(mBase + 32);

    // A-side global loads issued first.
    const float4 w0 = *(const float4*)(W   + nA * RANK + d8);
    const float4 w1 = *(const float4*)(W   + nA * RANK + d8 + 4);
    const float4 t0 = *(const float4*)(tau + nA * RANK + d8);
    const float4 t1 = *(const float4*)(tau + nA * RANK + d8 + 4);

    // Staging: copy the chunk (1920 x uint4) linearly into LDS.
    {
        const uint4* gsrc = (const uint4*)(P + (size_t)blockIdx.x * 15360);
        uint4* ldst = (uint4*)&sB[0][0][0];
        #pragma unroll
        for (int i = 0; i < 8; ++i) {
            const int idx = tid + (i << 8);
            if (idx < 1920) ldst[idx] = gsrc[idx];
        }
    }

    // A-fragment prologue (unchanged).
    const float wj[8] = {w0.x,w0.y,w0.z,w0.w,w1.x,w1.y,w1.z,w1.w};
    const float tj[8] = {t0.x,t0.y,t0.z,t0.w,t1.x,t1.y,t1.z,t1.w};
    unsigned uA[6][4];
    #pragma unroll
    for (int p = 0; p < 4; ++p) {
        float f0[6], f1[6];
        a_terms(wj[2*p],   tj[2*p],   mcF, f0);
        a_terms(wj[2*p+1], tj[2*p+1], mcF, f1);
        #pragma unroll
        for (int k = 0; k < 6; ++k) uA[k][p] = pack_bf16x2(f0[k], f1[k]);
    }
    bf16x8 fA[6];
    #pragma unroll
    for (int k = 0; k < 6; ++k) __builtin_memcpy(&fA[k], uA[k], 16);
    __syncthreads();

    for (int mt = 0; mt < 4; ++mt) {
        const int mL = (mt << 4) + l;
        const bf16x8 b0 = *(const bf16x8*)&sB[0][mL][d8];
        const bf16x8 b1 = *(const bf16x8*)&sB[1][mL][d8];
        const bf16x8 b2 = *(const bf16x8*)&sB[2][mL][d8];
        const bf16x8 b3 = *(const bf16x8*)&sB[3][mL][d8];
        const bf16x8 b4 = *(const bf16x8*)&sB[4][mL][d8];
        const bf16x8 b5 = *(const bf16x8*)&sB[5][mL][d8];

        f32x4 acc = {0.f, 0.f, 0.f, 0.f};
        acc = __builtin_amdgcn_mfma_f32_16x16x32_bf16(fA[0], b0, acc, 0, 0, 0);
        acc = __builtin_amdgcn_mfma_f32_16x16x32_bf16(fA[1], b1, acc, 0, 0, 0);
        acc = __builtin_amdgcn_mfma_f32_16x16x32_bf16(fA[2], b2, acc, 0, 0, 0);
        acc = __builtin_amdgcn_mfma_f32_16x16x32_bf16(fA[3], b3, acc, 0, 0, 0);
        acc = __builtin_amdgcn_mfma_f32_16x16x32_bf16(fA[4], b4, acc, 0, 0, 0);
        acc = __builtin_amdgcn_mfma_f32_16x16x32_bf16(fA[5], b5, acc, 0, 0, 0);

        #pragma unroll
        for (int r = 0; r < 4; ++r)
            out_f[(size_t)(nBase + wv * 16 + (q << 2) + r) * M
                  + mBase + (mt << 4) + l] = acc[r];
    }
}

// ===========================================================================
// dft_fused (no-ws fallback only — validated R5-R9, unchanged).
// ===========================================================================
__global__ __launch_bounds__(256) void dft_fused(const float* __restrict__ H,
                                                 float* __restrict__ HfR,
                                                 float* __restrict__ HfI) {
    __shared__ float  sh[M];
    __shared__ float2 sG[64 * 65];
    const int d = blockIdx.y, tid = threadIdx.x;
    for (int k = tid; k < M; k += 256) sh[k] = softplus_f(H[d * M + k]);
    __syncthreads();

    const int k0 = tid & 63;
    const int rB = (tid >> 6) * 16;
    float twR[16], twI[16], stR[16], stI[16], aR[16], aI[16];
    #pragma unroll
    for (int rr = 0; rr < 16; ++rr) {
        const float ang = (-2.0f * (float)M_PI / 64.0f) * (float)(rB + rr);
        __sincosf(ang, &stI[rr], &stR[rr]);
        twR[rr] = 1.f; twI[rr] = 0.f; aR[rr] = 0.f; aI[rr] = 0.f;
    }
    for (int k1 = 0; k1 < 64; ++k1) {
        const float h = sh[(k1 << 6) + k0];
        #pragma unroll
        for (int rr = 0; rr < 16; ++rr) {
            aR[rr] = fmaf(h, twR[rr], aR[rr]);
            aI[rr] = fmaf(h, twI[rr], aI[rr]);
            const float nR = fmaf(twR[rr], stR[rr], -twI[rr] * stI[rr]);
            const float nI = fmaf(twR[rr], stI[rr],  twI[rr] * stR[rr]);
            twR[rr] = nR; twI[rr] = nI;
        }
    }
    #pragma unroll
    for (int rr = 0; rr < 16; ++rr)
        sG[k0 * 65 + rB + rr] = make_float2(aR[rr], aI[rr]);
    __syncthreads();

    const int mBase = blockIdx.x * 1024;
    for (int j = 0; j < 4; ++j) {
        const int m = mBase + j * 256 + tid;
        const int r = m & 63;
        float ss, sc; __sincosf(PHI1 * (float)m, &ss, &sc);
        float tR_ = 1.f, tI_ = 0.f, accR = 0.f, accI = 0.f;
        #pragma unroll 8
        for (int qq = 0; qq < 64; ++qq) {
            const float2 g = sG[qq * 65 + r];
            accR = fmaf(tR_, g.x, fmaf(-tI_, g.y, accR));
            accI = fmaf(tR_, g.y, fmaf( tI_, g.x, accI));
            const float nR = fmaf(tR_, sc, -tI_ * ss);
            const float nI = fmaf(tR_, ss,  tI_ * sc);
            tR_ = nR; tI_ = nI;
        }
        HfR[d * M + m] = accR;
        HfI[d * M + m] = accI;
    }
}

// ===========================================================================
// VALU einsum v8 (validated R13) — kept for cplx / fallback paths (unchanged).
// ===========================================================================
template <bool CPLX, int U>
__global__ __launch_bounds__(256) void einsum_kernel(const float* __restrict__ W,
                                                     const float* __restrict__ tau,
                                                     const float* __restrict__ HfR,
                                                     const float* __restrict__ HfI,
                                                     float* __restrict__ out_f) {
    constexpr int ROWS = 16 * U;
    constexpr int MT   = 128;
    __shared__ float2 sHf[16 * MT];
    __shared__ float  sW[ROWS][RANK], sT[ROWS][RANK];
    const int tid   = threadIdx.x;
    const int mBase = blockIdx.x * MT;
    const int nBase = blockIdx.y * ROWS;

    for (int i = tid; i < ROWS * RANK; i += 256) {
        const int n_ = i >> 5, dd = i & 31;
        sW[n_][dd] = softplus_f(W[(nBase + n_) * RANK + dd]);
        sT[n_][dd] = tau[(nBase + n_) * RANK + dd];
    }

    const int nl = tid >> 4, chunk = tid & 15;
    const int m0 = mBase + (chunk << 3);

    float accR[U][8], accI[U][8];
    #pragma unroll
    for (int u = 0; u < U; ++u)
        #pragma unroll
        for (int j = 0; j < 8; ++j) { accR[u][j] = 0.f; if (CPLX) accI[u][j] = 0.f; }

    for (int half = 0; half < 2; ++half) {
        __syncthreads();
        for (int e = tid; e < 16 * 64; e += 256) {
            const int dl = e >> 6, p = e & 63;
            const int mm = p << 1;
            const int base = (half * 16 + dl) * M + mBase + mm;
            const float2 r2 = *(const float2*)(HfR + base);
            const float2 q2 = *(const float2*)(HfI + base);
            const int c = mm >> 3, j0 = mm & 7;
            float2* s2 = sHf + (dl << 7);
            s2[(j0 << 4) + c]       = make_float2(r2.x, q2.x);
            s2[((j0 + 1) << 4) + c] = make_float2(r2.y, q2.y);
        }
        __syncthreads();

        #pragma unroll 1
        for (int dl = 0; dl < 16; ++dl) {
            const int dd = (half << 4) + dl;
            float aR_[U], aI_[U], bR_[U], bI_[U], K[U];
            #pragma unroll
            for (int u = 0; u < U; ++u) {
                const float t = sT[nl * U + u][dd], w = sW[nl * U + u][dd];
                const float a1 = PHI1 * t;
                float sp, cp; __sincosf(a1, &sp, &cp);
                float s0, c0; __sincosf(a1 * (float)m0, &s0, &c0);
                aR_[u] = w * c0;
                aI_[u] = w * s0;
                bR_[u] = fmaf(aR_[u], cp, -aI_[u] * sp);
                bI_[u] = fmaf(aI_[u], cp,  aR_[u] * sp);
                K[u]   = 2.0f * cp;
            }
            int idx = (dl << 7) + chunk;
            #pragma unroll
            for (int j = 0; j < 8; ++j) {
                const float2 h = sHf[idx];
                #pragma unroll
                for (int u = 0; u < U; ++u) {
                    accR[u][j] = fmaf(aR_[u], h.x, fmaf(-aI_[u], h.y, accR[u][j]));
                    if (CPLX) accI[u][j] = fmaf(aR_[u], h.y, fmaf(aI_[u], h.x, accI[u][j]));
                    const float nR = fmaf(K[u], bR_[u], -aR_[u]);
                    const float nI = fmaf(K[u], bI_[u], -aI_[u]);
                    aR_[u] = bR_[u]; aI_[u] = bI_[u];
                    bR_[u] = nR;     bI_[u] = nI;
                }
                idx += 16;
            }
        }
    }

    #pragma unroll
    for (int u = 0; u < U; ++u) {
        const int n = nBase + nl * U + u;
        if (CPLX) {
            float2* o2 = ((float2*)out_f) + (size_t)n * M + m0;
            #pragma unroll
            for (int qq = 0; qq < 4; ++qq)
                ((float4*)o2)[qq] = make_float4(accR[u][2*qq], accI[u][2*qq],
                                                accR[u][2*qq+1], accI[u][2*qq+1]);
        } else {
            float* op = out_f + (size_t)n * M + m0;
            ((float4*)op)[0] = make_float4(accR[u][0], accR[u][1], accR[u][2], accR[u][3]);
            ((float4*)op)[1] = make_float4(accR[u][4], accR[u][5], accR[u][6], accR[u][7]);
        }
    }
}

// ===========================================================================
// Tail kernels (no-ws fallback only — dead given 268 MB ws, unchanged).
// ===========================================================================
__global__ __launch_bounds__(256) void tail_real(const float* __restrict__ W,
                                                 const float* __restrict__ tau,
                                                 const float* __restrict__ stashR,
                                                 const float* __restrict__ stashI,
                                                 float* __restrict__ out_f) {
    __shared__ float stR[32 * 32], stI[32 * 32];
    __shared__ float sW[64][RANK], sT[64][RANK];
    const int tid = threadIdx.x;
    const int c0  = blockIdx.x * 32;
    const int nBase = N - 64;
    for (int i = tid; i < 64 * RANK; i += 256) {
        const int n_ = i >> 5, dd = i & 31;
        sW[n_][dd] = softplus_f(W[(nBase + n_) * RANK + dd]);
        sT[n_][dd] = tau[(nBase + n_) * RANK + dd];
    }
    for (int i = tid; i < 32 * 32; i += 256) {
        const int d_ = i >> 5, mm = i & 31;
        stR[i] = stashR[d_ * M + c0 + mm];
        stI[i] = stashI[d_ * M + c0 + mm];
    }
    __syncthreads();
    const int n = tid >> 2, chunk = tid & 3;
    const int m0 = c0 + chunk;
    float acc[8];
    #pragma unroll
    for (int j = 0; j < 8; ++j) acc[j] = 0.f;
    for (int d = 0; d < RANK; ++d) {
        const float t = sT[n][d], w = sW[n][d];
        const float a1 = PHI1 * t;
        float ss, sc; __sincosf(a1 * 4.0f, &ss, &sc);
        float s0, c0f; __sincosf(a1 * (float)m0, &s0, &c0f);
        float tR_ = w * c0f, tI_ = w * s0;
        int idx = (d << 5) + chunk;
        #pragma unroll
        for (int j = 0; j < 8; ++j) {
            acc[j] = fmaf(tR_, stR[idx], fmaf(-tI_, stI[idx], acc[j]));
            const float nR = fmaf(tR_, sc, -tI_ * ss);
            const float nI = fmaf(tR_, ss,  tI_ * sc);
            tR_ = nR; tI_ = nI;
            idx += 4;
        }
    }
    #pragma unroll
    for (int j = 0; j < 8; ++j)
        out_f[(size_t)(nBase + n) * M + m0 + (j << 2)] = acc[j];
}

__global__ __launch_bounds__(256) void tail_cplx(const float* __restrict__ W,
                                                 const float* __restrict__ tau,
                                                 const float* __restrict__ stashR,
                                                 const float* __restrict__ stashI,
                                                 float* __restrict__ out_f) {
    const int nBase = N - 32;
    __shared__ float sW[32][RANK], sT[32][RANK];
    const int tid = threadIdx.x, mBase = blockIdx.x * 256;
    for (int i = tid; i < 32 * RANK; i += 256) {
        const int n_ = i >> 5, dd = i & 31;
        sW[n_][dd] = softplus_f(W[(nBase + n_) * RANK + dd]);
        sT[n_][dd] = tau[(nBase + n_) * RANK + dd];
    }
    const int m = mBase + tid;
    float hr[RANK], hi[RANK];
    #pragma unroll
    for (int d = 0; d < RANK; ++d) { hr[d] = stashR[d * M + m]; hi[d] = stashI[d * M + m]; }
    __syncthreads();
    const float phi = PHI1 * (float)m;
    for (int n_ = 0; n_ < 32; ++n_) {
        float aR = 0.f, aI = 0.f;
        #pragma unroll
        for (int d = 0; d < RANK; ++d) {
            const float t = sT[n_][d], w = sW[n_][d];
            float s, c; __sincosf(t * phi, &s, &c);
            const float cw = c * w, sw = s * w;
            aR = fmaf(cw, hr[d], fmaf(-sw, hi[d], aR));
            aI = fmaf(cw, hi[d], fmaf( sw, hr[d], aI));
        }
        ((float2*)out_f)[(size_t)(nBase + n_) * M + m] = make_float2(aR, aI);
    }
}

// ---------------------------------------------------------------------------
extern "C" void kernel_launch(void* const* d_in, const int* in_sizes, int n_in,
                              void* d_out, int out_size, void* d_ws, size_t ws_size,
                              hipStream_t stream) {
    const float* W   = (const float*)d_in[0];
    const float* H   = (const float*)d_in[1];
    const float* tau = (const float*)d_in[2];
    float* out_f = (float*)d_out;

    const bool   cplx   = (out_size >= 2 * N * M);
    const size_t planeN = (size_t)RANK * M;            // 131072 floats / plane

    if (d_ws != nullptr && ws_size >= 4 * planeN * sizeof(float)) {
        if (!cplx) {
            // R22: dft_plane (mod-16, emits bf16 B-planes) -> einsum copy-staged.
            unsigned short* P = (unsigned short*)d_ws;   // 64 chunks x 30720 B
            dft_plane<<<dim3(16, 32), 256, 0, stream>>>(H, P);
            einsum_mfma<<<dim3(64, 16), 256, 0, stream>>>(W, tau, P, out_f);
        } else {
            float* HfR = (float*)d_ws;
            float* HfI = HfR + planeN;
            dft_bal<<<dim3(8, 32), 256, 0, stream>>>(H, HfR, HfI);
            einsum_kernel<true , 2><<<dim3(32, N / 32), 256, 0, stream>>>(W, tau, HfR, HfI, out_f);
        }
    } else if (!cplx) {
        float* HfR = out_f + (size_t)(N - 64) * M;     // stash in last 64 real rows
        float* HfI = HfR + planeN;
        dft_fused<<<dim3(4, 32), 256, 0, stream>>>(H, HfR, HfI);
        einsum_kernel<false, 2><<<dim3(32, (N - 64) / 32), 256, 0, stream>>>(W, tau, HfR, HfI, out_f);
        tail_real<<<dim3(128), 256, 0, stream>>>(W, tau, HfR, HfI, out_f);
    } else {
        float* HfR = out_f + 2 * (size_t)N * M - 2 * planeN;  // last 32 cplx rows
        float* HfI = HfR + planeN;
        dft_fused<<<dim3(4, 32), 256, 0, stream>>>(H, HfR, HfI);
        einsum_kernel<true , 2><<<dim3(32, (N - 32) / 32), 256, 0, stream>>>(W, tau, HfR, HfI, out_f);
        tail_cplx<<<dim3(16), 256, 0, stream>>>(W, tau, HfR, HfI, out_f);
    }
}